// Round 14
// baseline (44.212 us; speedup 1.0000x reference)
//
#include <hip/hip_runtime.h>
#include <stdint.h>

#define TT 256
#define BB 2048
#define AA 18
#define NTB (TT * BB)
#define WPB 4          // waves per block
#define SEGLEN 2       // timesteps per wave
#define TPB 8          // timesteps per block
#define NTBLK 32       // TT / TPB
#define NBLK 1024      // 32 col-groups * 32 time-blocks
#define REPS 4         // DIAGNOSTIC: replicate policy/behavior phase 4x
#define LN2 0.69314718055994531f

// ws: pe[NBLK], pv[NBLK], pp[NBLK], fsv[8], fsp[8], wsf[5][NTBLK][BB] (1.25 MB)
// Fence-free 3-node structure (R10/R11 skeleton). THIS ROUND ONLY: the
// entropy+gather phase runs REPS times (rotated col-groups, replicas 1..3
// kept live via asm sinks, results discarded) so main_k exceeds the ~40us
// harness fills and surfaces in the rocprof top-5 with counters.

__global__ __launch_bounds__(256) void main_k(
    const float* __restrict__ policy,
    const float* __restrict__ behavior,
    const float* __restrict__ rewards,
    const float* __restrict__ values,
    const float* __restrict__ next_values,
    const int* __restrict__ actions,
    const void* __restrict__ done,
    float* __restrict__ pe, float* __restrict__ pv, float* __restrict__ pp,
    float* __restrict__ wsf)
{
    int tid = threadIdx.x;
    int lane = tid & 63;
    int w = tid >> 6;                 // wave 0..3
    int bid = blockIdx.x;
    int g = bid >> 5;                 // col-group 0..31
    int tb = bid & 31;                // time-block 0..31

    __shared__ float tup[WPB][5][64]; // 5 KB tuple buffer
    __shared__ float red[WPB][3];

    // per-wave done-layout detection (4KB scan, wave-uniform, no barrier)
    const int* di = (const int*)done;
    int bad = 0;
#pragma unroll
    for (int i = 0; i < 16; ++i) {
        int v = di[lane + 64 * i];
        bad |= !(v == 0 || v == 1 || v == 0x3F800000);
    }
    bool bytelay = (__any(bad) != 0);
    const uint8_t* d8 = (const uint8_t*)done;

    int tA = tb * TPB + w * SEGLEN + 1;   // later step, processed first
    int tB = tA - 1;

    // ---- replicated streaming/gather phase (diagnostic) ----
    float ent2 = 0.f, piA = 1.f, muA = 1.f, piB = 1.f, muB = 1.f;
#pragma unroll
    for (int rep = 0; rep < REPS; ++rep) {
        int grot = (g + rep * 8) & 31;        // rep 0 == real col-group
        int bb = grot * 64 + lane;
        int rAr = tA * BB + bb, rBr = tB * BB + bb;
        int aAr = actions[rAr], aBr = actions[rBr];
        float piAr = policy[(size_t)rAr * AA + aAr];
        float muAr = behavior[(size_t)rAr * AA + aAr];
        float piBr = policy[(size_t)rBr * AA + aBr];
        float muBr = behavior[(size_t)rBr * AA + aBr];
        float ent2r = 0.f;
        const float* gA = policy + (size_t)(tA * BB + grot * 64) * AA;
        const float* gB = policy + (size_t)(tB * BB + grot * 64) * AA;
#pragma unroll
        for (int k = 0; k < 9; ++k) {
            float2 v = *(const float2*)(gA + 2 * (lane + 64 * k));
            ent2r = fmaf(v.x, __log2f(v.x + 1e-10f), ent2r);
            ent2r = fmaf(v.y, __log2f(v.y + 1e-10f), ent2r);
        }
#pragma unroll
        for (int k = 0; k < 9; ++k) {
            float2 v = *(const float2*)(gB + 2 * (lane + 64 * k));
            ent2r = fmaf(v.x, __log2f(v.x + 1e-10f), ent2r);
            ent2r = fmaf(v.y, __log2f(v.y + 1e-10f), ent2r);
        }
        if (rep == 0) {
            ent2 = ent2r; piA = piAr; muA = muAr; piB = piBr; muB = muBr;
        } else {
            // keep replica work live without affecting results (rule #17)
            asm volatile("" :: "v"(ent2r), "v"(piAr), "v"(muAr),
                              "v"(piBr), "v"(muBr));
        }
    }

    // ---- real computation (identical to R11; replica-0 values) ----
    int b = g * 64 + lane;
    int rA = tA * BB + b, rB = tB * BB + b;
    float rwA = rewards[rA], rwB = rewards[rB];
    float v0A = values[rA],  v0B = values[rB];
    float nvA = next_values[rA], nvB = next_values[rB];
    int dnA = bytelay ? (int)d8[rA] : di[rA];
    int dnB = bytelay ? (int)d8[rB] : di[rB];
    float vtA = (tA == TT - 1) ? nvA : values[rA + BB];
    float vtB = v0A;                      // values[tB+1] == values[tA]

    float vacc = 0.f, P = 1.f;
    float sv0 = 0.f, sv1 = 0.f, sv2 = 0.f, sp0 = 0.f, sp1 = 0.f;

    auto step = [&](float pi, float mu, float rw, float v0, float nv,
                    int dn, float vt1) {
        float lpi = LN2 * __log2f(pi + 1e-10f);
        float c = fminf(1.0f, pi / mu);
        float disc = dn ? 0.f : 0.99f;
        float cr = fminf(1.f, fmaxf(-1.f, rw));
        float base = cr - v0;
        float dlt = c * fmaf(disc, vt1, base);
        float gg = disc * c;
        vacc = fmaf(gg, vacc, dlt);          // local value (zero carry)
        P *= gg;                             // carry coefficient
        sv0 = fmaf(vacc, vacc, sv0);
        sv1 = fmaf(P, vacc, sv1);
        sv2 = fmaf(P, P, sv2);
        float adv = c * fmaf(disc, nv, base);
        float q = fmaf(disc, v0, base);
        float al = adv * lpi;
        sp0 = fmaf(al, fmaf(disc, vacc, q), sp0);
        sp1 = fmaf(al * disc, P, sp1);
    };

    step(piA, muA, rwA, v0A, nvA, dnA, vtA);
    step(piB, muB, rwB, v0B, nvB, dnB, vtB);

    // stash wave tuple; wave-reduce carry-independent sums
    tup[w][0][lane] = P;
    tup[w][1][lane] = vacc;
    tup[w][2][lane] = sv1;
    tup[w][3][lane] = sv2;
    tup[w][4][lane] = sp1;
    float ent = LN2 * ent2;
    for (int off = 32; off > 0; off >>= 1) {
        ent += __shfl_down(ent, off);
        sv0 += __shfl_down(sv0, off);
        sp0 += __shfl_down(sp0, off);
    }
    if (lane == 0) { red[w][0] = ent; red[w][1] = sv0; red[w][2] = sp0; }
    __syncthreads();   // the ONLY block barrier

    if (w == 0) {
        // compose 4 wave tuples (wave 3 = latest timesteps); column = lane
        float A  = tup[3][0][lane];
        float Bv = tup[3][1][lane];
        float s1 = tup[3][2][lane];
        float s2 = tup[3][3][lane];
        float p1 = tup[3][4][lane];
        float svx = 0.f, spx = 0.f;
#pragma unroll
        for (int s = WPB - 2; s >= 0; --s) {
            float Al  = tup[s][0][lane];
            float Bl  = tup[s][1][lane];
            float s1l = tup[s][2][lane];
            float s2l = tup[s][3][lane];
            float p1l = tup[s][4][lane];
            svx = fmaf(2.f * Bv, s1l, svx);
            svx = fmaf(Bv * Bv, s2l, svx);
            spx = fmaf(Bv, p1l, spx);
            s1 = fmaf(A, fmaf(Bv, s2l, s1l), s1);
            s2 = fmaf(A * A, s2l, s2);
            p1 = fmaf(A, p1l, p1);
            Bv = fmaf(Al, Bv, Bl);
            A  = A * Al;
        }
        int col = g * 64 + lane;
        wsf[(0 * NTBLK + tb) * BB + col] = A;
        wsf[(1 * NTBLK + tb) * BB + col] = Bv;
        wsf[(2 * NTBLK + tb) * BB + col] = s1;
        wsf[(3 * NTBLK + tb) * BB + col] = s2;
        wsf[(4 * NTBLK + tb) * BB + col] = p1;
        for (int off = 32; off > 0; off >>= 1) {
            svx += __shfl_down(svx, off);
            spx += __shfl_down(spx, off);
        }
        if (lane == 0) {
            pe[bid] = red[0][0] + red[1][0] + red[2][0] + red[3][0];
            pv[bid] = red[0][1] + red[1][1] + red[2][1] + red[3][1] + svx;
            pp[bid] = red[0][2] + red[1][2] + red[2][2] + red[3][2] + spx;
        }
    }
}

// Fold 32 composed tuples per column. 8 blocks x 256 threads, thread = column.
__global__ __launch_bounds__(256) void fold_k(
    const float* __restrict__ wsf,
    float* __restrict__ fsv, float* __restrict__ fsp)
{
    int tid = threadIdx.x;
    int col = blockIdx.x * 256 + tid;     // 0..2047
    float C = 0.f, svT = 0.f, spT = 0.f;
#pragma unroll 8
    for (int tb2 = NTBLK - 1; tb2 >= 0; --tb2) {
        float A  = wsf[(0 * NTBLK + tb2) * BB + col];
        float Bv = wsf[(1 * NTBLK + tb2) * BB + col];
        float s1 = wsf[(2 * NTBLK + tb2) * BB + col];
        float s2 = wsf[(3 * NTBLK + tb2) * BB + col];
        float p1 = wsf[(4 * NTBLK + tb2) * BB + col];
        svT = fmaf(2.f * C, s1, svT);
        svT = fmaf(C * C, s2, svT);
        spT = fmaf(C, p1, spT);
        C = fmaf(A, C, Bv);
    }
    for (int off = 32; off > 0; off >>= 1) {
        svT += __shfl_down(svT, off);
        spT += __shfl_down(spT, off);
    }
    __shared__ float s1r[4], s2r[4];
    int lane = tid & 63, w = tid >> 6;
    if (lane == 0) { s1r[w] = svT; s2r[w] = spT; }
    __syncthreads();
    if (tid == 0) {
        fsv[blockIdx.x] = s1r[0] + s1r[1] + s1r[2] + s1r[3];
        fsp[blockIdx.x] = s2r[0] + s2r[1] + s2r[2] + s2r[3];
    }
}

__global__ __launch_bounds__(256) void final_k(
    const float* __restrict__ pe, const float* __restrict__ pv,
    const float* __restrict__ pp, const float* __restrict__ fsv,
    const float* __restrict__ fsp, float* __restrict__ out)
{
    int tid = threadIdx.x;
    float e = 0.f, v = 0.f, p = 0.f;
#pragma unroll
    for (int i = 0; i < NBLK / 256; ++i) {
        int j = tid + 256 * i;
        e += pe[j];
        v += pv[j];
        p += pp[j];
    }
    if (tid < 8) { v += fsv[tid]; p += fsp[tid]; }
    for (int off = 32; off > 0; off >>= 1) {
        e += __shfl_down(e, off);
        v += __shfl_down(v, off);
        p += __shfl_down(p, off);
    }
    __shared__ float s0[4], s1[4], s2[4];
    int lane = tid & 63, w = tid >> 6;
    if (lane == 0) { s0[w] = e; s1[w] = v; s2[w] = p; }
    __syncthreads();
    if (tid == 0) {
        double E  = (double)s0[0] + s0[1] + s0[2] + s0[3];
        double V  = (double)s1[0] + s1[1] + s1[2] + s1[3];
        double Pp = (double)s2[0] + s2[1] + s2[2] + s2[3];
        // loss = (S_val - S_pol - 0.01*S_ent) / NTB
        out[0] = (float)((V - Pp - 0.01 * E) / (double)NTB);
    }
}

extern "C" void kernel_launch(void* const* d_in, const int* in_sizes, int n_in,
                              void* d_out, int out_size, void* d_ws, size_t ws_size,
                              hipStream_t stream) {
    const float* policy      = (const float*)d_in[0];
    const float* behavior    = (const float*)d_in[1];
    const float* rewards     = (const float*)d_in[2];
    const float* values      = (const float*)d_in[3];
    const float* next_values = (const float*)d_in[4];
    const int*   actions     = (const int*)d_in[5];
    const void*  done        = d_in[6];

    float* pe  = (float*)d_ws;
    float* pv  = pe + NBLK;
    float* pp  = pv + NBLK;
    float* fsv = pp + NBLK;
    float* fsp = fsv + 8;
    float* wsf = fsp + 8;

    main_k<<<NBLK, 256, 0, stream>>>(policy, behavior, rewards, values,
                                     next_values, actions, done,
                                     pe, pv, pp, wsf);
    fold_k<<<8, 256, 0, stream>>>(wsf, fsv, fsp);
    final_k<<<1, 256, 0, stream>>>(pe, pv, pp, fsv, fsp, (float*)d_out);
}

// Round 15
// 27.014 us; speedup vs baseline: 1.6366x; 1.6366x over previous
//
#include <hip/hip_runtime.h>
#include <stdint.h>

#define TT 256
#define BB 2048
#define AA 18
#define NTB (TT * BB)
#define WPB 4          // waves per block
#define SEGLEN 2       // timesteps per wave
#define TPB 8          // timesteps per block
#define NTBLK 32       // TT / TPB
#define NBLK 1024      // 32 col-groups * 32 time-blocks
#define LN2 0.69314718055994531f

// ws: pe[NBLK], pv[NBLK], pp[NBLK], fsv[8], fsp[8], wsf[5][NTBLK][BB] (1.25 MB)
// Fence-free 3-node skeleton (R10/R11). R15: phase restructured for per-thread
// MLP — tile loads as 4xfloat4+1xfloat2, all loads issued before any compute.

__global__ __launch_bounds__(256) void main_k(
    const float* __restrict__ policy,
    const float* __restrict__ behavior,
    const float* __restrict__ rewards,
    const float* __restrict__ values,
    const float* __restrict__ next_values,
    const int* __restrict__ actions,
    const void* __restrict__ done,
    float* __restrict__ pe, float* __restrict__ pv, float* __restrict__ pp,
    float* __restrict__ wsf)
{
    int tid = threadIdx.x;
    int lane = tid & 63;
    int w = tid >> 6;                 // wave 0..3
    int bid = blockIdx.x;
    int g = bid >> 5;                 // col-group 0..31
    int tb = bid & 31;                // time-block 0..31

    __shared__ float tup[WPB][5][64]; // 5 KB tuple buffer
    __shared__ float red[WPB][3];

    int b = g * 64 + lane;
    int tA = tb * TPB + w * SEGLEN + 1;   // later step, processed first
    int tB = tA - 1;
    int rA = tA * BB + b, rB = tB * BB + b;

    // ---------- ISSUE PHASE: all independent loads first ----------
    // actions first (the pi/mu gathers depend on them)
    int aA = actions[rA], aB = actions[rB];

    // wide policy-tile loads: tile = 1152 contiguous floats = 256 float4 + 64 float2
    const float4* pA4 = (const float4*)(policy + (size_t)(tA * BB + g * 64) * AA);
    const float4* pB4 = (const float4*)(policy + (size_t)(tB * BB + g * 64) * AA);
    float4 A0 = pA4[lane], A1 = pA4[lane + 64], A2 = pA4[lane + 128], A3 = pA4[lane + 192];
    float4 B0 = pB4[lane], B1 = pB4[lane + 64], B2 = pB4[lane + 128], B3 = pB4[lane + 192];
    float2 A4 = ((const float2*)(pA4 + 256))[lane];
    float2 B4 = ((const float2*)(pB4 + 256))[lane];

    // scalar arrays
    float rwA = rewards[rA], rwB = rewards[rB];
    float v0A = values[rA],  v0B = values[rB];
    float nvA = next_values[rA], nvB = next_values[rB];
    const int* di = (const int*)done;
    const uint8_t* d8 = (const uint8_t*)done;

    // done-layout detect (4KB scan, L2-hot)
    int bad = 0;
#pragma unroll
    for (int i = 0; i < 16; ++i) {
        int v = di[lane + 64 * i];
        bad |= !(v == 0 || v == 1 || v == 0x3F800000);
    }
    bool bytelay = (__any(bad) != 0);
    int dnA = bytelay ? (int)d8[rA] : di[rA];
    int dnB = bytelay ? (int)d8[rB] : di[rB];

    // gathers (dependent on aA/aB; policy lines L1-hot from the stream)
    float piA = policy[(size_t)rA * AA + aA];
    float muA = behavior[(size_t)rA * AA + aA];
    float piB = policy[(size_t)rB * AA + aB];
    float muB = behavior[(size_t)rB * AA + aB];

    float vtA = (tA == TT - 1) ? nvA : values[rA + BB];
    float vtB = v0A;                      // values[tB+1] == values[tA]

    // ---------- COMPUTE PHASE ----------
    float ent2 = 0.f;
    auto e4 = [&](float4 v) {
        ent2 = fmaf(v.x, __log2f(v.x + 1e-10f), ent2);
        ent2 = fmaf(v.y, __log2f(v.y + 1e-10f), ent2);
        ent2 = fmaf(v.z, __log2f(v.z + 1e-10f), ent2);
        ent2 = fmaf(v.w, __log2f(v.w + 1e-10f), ent2);
    };
    e4(A0); e4(A1); e4(A2); e4(A3);
    e4(B0); e4(B1); e4(B2); e4(B3);
    ent2 = fmaf(A4.x, __log2f(A4.x + 1e-10f), ent2);
    ent2 = fmaf(A4.y, __log2f(A4.y + 1e-10f), ent2);
    ent2 = fmaf(B4.x, __log2f(B4.x + 1e-10f), ent2);
    ent2 = fmaf(B4.y, __log2f(B4.y + 1e-10f), ent2);

    float vacc = 0.f, P = 1.f;
    float sv0 = 0.f, sv1 = 0.f, sv2 = 0.f, sp0 = 0.f, sp1 = 0.f;

    auto step = [&](float pi, float mu, float rw, float v0, float nv,
                    int dn, float vt1) {
        float lpi = LN2 * __log2f(pi + 1e-10f);
        float c = fminf(1.0f, pi / mu);
        float disc = dn ? 0.f : 0.99f;
        float cr = fminf(1.f, fmaxf(-1.f, rw));
        float base = cr - v0;
        float dlt = c * fmaf(disc, vt1, base);
        float gg = disc * c;
        vacc = fmaf(gg, vacc, dlt);          // local value (zero carry)
        P *= gg;                             // carry coefficient
        sv0 = fmaf(vacc, vacc, sv0);
        sv1 = fmaf(P, vacc, sv1);
        sv2 = fmaf(P, P, sv2);
        float adv = c * fmaf(disc, nv, base);
        float q = fmaf(disc, v0, base);
        float al = adv * lpi;
        sp0 = fmaf(al, fmaf(disc, vacc, q), sp0);
        sp1 = fmaf(al * disc, P, sp1);
    };

    step(piA, muA, rwA, v0A, nvA, dnA, vtA);
    step(piB, muB, rwB, v0B, nvB, dnB, vtB);

    // stash wave tuple; wave-reduce carry-independent sums
    tup[w][0][lane] = P;
    tup[w][1][lane] = vacc;
    tup[w][2][lane] = sv1;
    tup[w][3][lane] = sv2;
    tup[w][4][lane] = sp1;
    float ent = LN2 * ent2;
    for (int off = 32; off > 0; off >>= 1) {
        ent += __shfl_down(ent, off);
        sv0 += __shfl_down(sv0, off);
        sp0 += __shfl_down(sp0, off);
    }
    if (lane == 0) { red[w][0] = ent; red[w][1] = sv0; red[w][2] = sp0; }
    __syncthreads();   // the ONLY block barrier

    if (w == 0) {
        // compose 4 wave tuples (wave 3 = latest timesteps); column = lane
        float A  = tup[3][0][lane];
        float Bv = tup[3][1][lane];
        float s1 = tup[3][2][lane];
        float s2 = tup[3][3][lane];
        float p1 = tup[3][4][lane];
        float svx = 0.f, spx = 0.f;
#pragma unroll
        for (int s = WPB - 2; s >= 0; --s) {
            float Al  = tup[s][0][lane];
            float Bl  = tup[s][1][lane];
            float s1l = tup[s][2][lane];
            float s2l = tup[s][3][lane];
            float p1l = tup[s][4][lane];
            svx = fmaf(2.f * Bv, s1l, svx);
            svx = fmaf(Bv * Bv, s2l, svx);
            spx = fmaf(Bv, p1l, spx);
            s1 = fmaf(A, fmaf(Bv, s2l, s1l), s1);
            s2 = fmaf(A * A, s2l, s2);
            p1 = fmaf(A, p1l, p1);
            Bv = fmaf(Al, Bv, Bl);
            A  = A * Al;
        }
        int col = g * 64 + lane;
        wsf[(0 * NTBLK + tb) * BB + col] = A;
        wsf[(1 * NTBLK + tb) * BB + col] = Bv;
        wsf[(2 * NTBLK + tb) * BB + col] = s1;
        wsf[(3 * NTBLK + tb) * BB + col] = s2;
        wsf[(4 * NTBLK + tb) * BB + col] = p1;
        for (int off = 32; off > 0; off >>= 1) {
            svx += __shfl_down(svx, off);
            spx += __shfl_down(spx, off);
        }
        if (lane == 0) {
            pe[bid] = red[0][0] + red[1][0] + red[2][0] + red[3][0];
            pv[bid] = red[0][1] + red[1][1] + red[2][1] + red[3][1] + svx;
            pp[bid] = red[0][2] + red[1][2] + red[2][2] + red[3][2] + spx;
        }
    }
}

// Fold 32 composed tuples per column. 8 blocks x 256 threads, thread = column.
__global__ __launch_bounds__(256) void fold_k(
    const float* __restrict__ wsf,
    float* __restrict__ fsv, float* __restrict__ fsp)
{
    int tid = threadIdx.x;
    int col = blockIdx.x * 256 + tid;     // 0..2047
    float C = 0.f, svT = 0.f, spT = 0.f;
#pragma unroll 8
    for (int tb2 = NTBLK - 1; tb2 >= 0; --tb2) {
        float A  = wsf[(0 * NTBLK + tb2) * BB + col];
        float Bv = wsf[(1 * NTBLK + tb2) * BB + col];
        float s1 = wsf[(2 * NTBLK + tb2) * BB + col];
        float s2 = wsf[(3 * NTBLK + tb2) * BB + col];
        float p1 = wsf[(4 * NTBLK + tb2) * BB + col];
        svT = fmaf(2.f * C, s1, svT);
        svT = fmaf(C * C, s2, svT);
        spT = fmaf(C, p1, spT);
        C = fmaf(A, C, Bv);
    }
    for (int off = 32; off > 0; off >>= 1) {
        svT += __shfl_down(svT, off);
        spT += __shfl_down(spT, off);
    }
    __shared__ float s1r[4], s2r[4];
    int lane = tid & 63, w = tid >> 6;
    if (lane == 0) { s1r[w] = svT; s2r[w] = spT; }
    __syncthreads();
    if (tid == 0) {
        fsv[blockIdx.x] = s1r[0] + s1r[1] + s1r[2] + s1r[3];
        fsp[blockIdx.x] = s2r[0] + s2r[1] + s2r[2] + s2r[3];
    }
}

__global__ __launch_bounds__(256) void final_k(
    const float* __restrict__ pe, const float* __restrict__ pv,
    const float* __restrict__ pp, const float* __restrict__ fsv,
    const float* __restrict__ fsp, float* __restrict__ out)
{
    int tid = threadIdx.x;
    float e = 0.f, v = 0.f, p = 0.f;
#pragma unroll
    for (int i = 0; i < NBLK / 256; ++i) {
        int j = tid + 256 * i;
        e += pe[j];
        v += pv[j];
        p += pp[j];
    }
    if (tid < 8) { v += fsv[tid]; p += fsp[tid]; }
    for (int off = 32; off > 0; off >>= 1) {
        e += __shfl_down(e, off);
        v += __shfl_down(v, off);
        p += __shfl_down(p, off);
    }
    __shared__ float s0[4], s1[4], s2[4];
    int lane = tid & 63, w = tid >> 6;
    if (lane == 0) { s0[w] = e; s1[w] = v; s2[w] = p; }
    __syncthreads();
    if (tid == 0) {
        double E  = (double)s0[0] + s0[1] + s0[2] + s0[3];
        double V  = (double)s1[0] + s1[1] + s1[2] + s1[3];
        double Pp = (double)s2[0] + s2[1] + s2[2] + s2[3];
        // loss = (S_val - S_pol - 0.01*S_ent) / NTB
        out[0] = (float)((V - Pp - 0.01 * E) / (double)NTB);
    }
}

extern "C" void kernel_launch(void* const* d_in, const int* in_sizes, int n_in,
                              void* d_out, int out_size, void* d_ws, size_t ws_size,
                              hipStream_t stream) {
    const float* policy      = (const float*)d_in[0];
    const float* behavior    = (const float*)d_in[1];
    const float* rewards     = (const float*)d_in[2];
    const float* values      = (const float*)d_in[3];
    const float* next_values = (const float*)d_in[4];
    const int*   actions     = (const int*)d_in[5];
    const void*  done        = d_in[6];

    float* pe  = (float*)d_ws;
    float* pv  = pe + NBLK;
    float* pp  = pv + NBLK;
    float* fsv = pp + NBLK;
    float* fsp = fsv + 8;
    float* wsf = fsp + 8;

    main_k<<<NBLK, 256, 0, stream>>>(policy, behavior, rewards, values,
                                     next_values, actions, done,
                                     pe, pv, pp, wsf);
    fold_k<<<8, 256, 0, stream>>>(wsf, fsv, fsp);
    final_k<<<1, 256, 0, stream>>>(pe, pv, pp, fsv, fsp, (float*)d_out);
}